// Round 1
// baseline (846.648 us; speedup 1.0000x reference)
//
#include <hip/hip_runtime.h>

#define EN 200000
#define TN 1500000

typedef short s16x8 __attribute__((ext_vector_type(8)));
typedef float f32x4 __attribute__((ext_vector_type(4)));

// ---- packed weight offsets (ushort units) ----
#define WJI   0
#define WKJ   16384
#define WDOWN 32768
#define WUP   40960
#define WB0   49152
#define WB1   65536
#define WLIN  81920
#define WA00  98304
#define WA01  114688
#define WA10  131072
#define WA11  147456
#define WSBFP 163840
#define WP_COUNT 167936

// ---- workspace byte offsets ----
#define AGG_BYTES   (EN * 64 * 4)            // 51,200,000
#define XD_OFF_B    AGG_BYTES
#define WP_OFF_B    (2 * AGG_BYTES)          // 102,400,000 (16B aligned)
#define WRBFC_OFF_B (WP_OFF_B + WP_COUNT * 2)
#define WSBFC_OFF_B (WRBFC_OFF_B + 768 * 4)

__device__ __forceinline__ unsigned short f2bf(float f) {
    unsigned int b = __float_as_uint(f);
    b += 0x7FFFu + ((b >> 16) & 1u);
    return (unsigned short)(b >> 16);
}
__device__ __forceinline__ float bf2f(unsigned short u) {
    return __uint_as_float(((unsigned int)u) << 16);
}
__device__ __forceinline__ float silu_f(float v) {
    return v / (1.f + __expf(-v));
}

#define MFMA(a, b, c) __builtin_amdgcn_mfma_f32_16x16x32_bf16((a), (b), (c), 0, 0, 0)

// ============ prep1: combine tiny basis weight pairs ============
__global__ void k_prep1(const float* __restrict__ Wr1, const float* __restrict__ Wr2,
                        const float* __restrict__ Ws1, const float* __restrict__ Ws2,
                        float* __restrict__ wrbfc, float* __restrict__ wsbfc) {
    int idx = blockIdx.x * 256 + threadIdx.x;
    if (idx < 768) {  // [6][128]
        int r = idx >> 7, c = idx & 127;
        float s = 0.f;
        #pragma unroll
        for (int m = 0; m < 8; m++) s += Wr1[r * 8 + m] * Wr2[m * 128 + c];
        wrbfc[idx] = s;
    }
    int i2 = idx - 768;
    if (i2 >= 0 && i2 < 2688) {  // [42][64]
        int r = i2 >> 6, c = i2 & 63;
        float s = 0.f;
        #pragma unroll
        for (int m = 0; m < 8; m++) s += Ws1[r * 8 + m] * Ws2[m * 64 + c];
        wsbfc[i2] = s;
    }
}

// ============ prep2: pack weights into MFMA B-fragment layout ============
// layout: dst[((ks*(N/16)+cb)*64+lane)*8+j] = src[(ks*32+(lane>>4)*8+j)*N + cb*16+(lane&15)]
__global__ void k_prep2(const float* __restrict__ Wji, const float* __restrict__ Wkj,
                        const float* __restrict__ Wdown, const float* __restrict__ Wup,
                        const float* __restrict__ Wbef, const float* __restrict__ Wlin,
                        const float* __restrict__ Waft, const float* __restrict__ wsbfc,
                        unsigned short* __restrict__ wp) {
    for (int idx = blockIdx.x * 256 + threadIdx.x; idx < WP_COUNT; idx += gridDim.x * 256) {
        const float* src;
        int off, N;
        bool pad42 = false;
        if (idx < WKJ)        { src = Wji;           off = WJI;   N = 128; }
        else if (idx < WDOWN) { src = Wkj;           off = WKJ;   N = 128; }
        else if (idx < WUP)   { src = Wdown;         off = WDOWN; N = 64;  }
        else if (idx < WB0)   { src = Wup;           off = WUP;   N = 128; }
        else if (idx < WB1)   { src = Wbef;          off = WB0;   N = 128; }
        else if (idx < WLIN)  { src = Wbef + 16384;  off = WB1;   N = 128; }
        else if (idx < WA00)  { src = Wlin;          off = WLIN;  N = 128; }
        else if (idx < WA01)  { src = Waft;          off = WA00;  N = 128; }
        else if (idx < WA10)  { src = Waft + 16384;  off = WA01;  N = 128; }
        else if (idx < WA11)  { src = Waft + 32768;  off = WA10;  N = 128; }
        else if (idx < WSBFP) { src = Waft + 49152;  off = WA11;  N = 128; }
        else                  { src = wsbfc;         off = WSBFP; N = 64; pad42 = true; }
        int li = idx - off;
        int j = li & 7, lane = (li >> 3) & 63, rest = li >> 9;
        int ncb = N >> 4;
        int cb = rest % ncb, ks = rest / ncb;
        int k = ks * 32 + ((lane >> 4) << 3) + j;
        int n = cb * 16 + (lane & 15);
        float v = 0.f;
        if (!pad42 || k < 42) v = src[k * N + n];
        wp[idx] = f2bf(v);
    }
}

// ============ K1: edge stage 1 ============
__global__ __launch_bounds__(256) void k_edge1(
        const float* __restrict__ x, const float* __restrict__ rbf,
        const float* __restrict__ bkj, const float* __restrict__ bji,
        const unsigned short* __restrict__ wp, const float* __restrict__ wrbfc,
        float* __restrict__ xji, float* __restrict__ xd) {
    __shared__ unsigned short xa[64 * 136];
    __shared__ unsigned short kjt[64 * 136];
    __shared__ unsigned short rp[64 * 128];
    const int tid = threadIdx.x;
    const int row0 = blockIdx.x * 64;
    // stage x tile as bf16
    {
        const float4* src = (const float4*)(x + (size_t)row0 * 128);
        #pragma unroll
        for (int k = 0; k < 8; k++) {
            int idx = tid + k * 256;
            float4 v = src[idx];
            int flat = idx << 2, r = flat >> 7, c = flat & 127;
            ushort4 u; u.x = f2bf(v.x); u.y = f2bf(v.y); u.z = f2bf(v.z); u.w = f2bf(v.w);
            *(ushort4*)&xa[r * 136 + c] = u;
        }
    }
    // rbf_p tile (bf16)
    #pragma unroll
    for (int k = 0; k < 32; k++) {
        int idx = tid + k * 256;
        int r = idx >> 7, c = idx & 127;
        const float* rb = rbf + (size_t)(row0 + r) * 6;
        float s = rb[0] * wrbfc[c] + rb[1] * wrbfc[128 + c] + rb[2] * wrbfc[256 + c]
                + rb[3] * wrbfc[384 + c] + rb[4] * wrbfc[512 + c] + rb[5] * wrbfc[640 + c];
        rp[idx] = f2bf(s);
    }
    __syncthreads();
    const int w = tid >> 6, l = tid & 63, l15 = l & 15, l4 = l >> 4;
    s16x8 af[4];
    {
        const unsigned short* ab = &xa[(w * 16 + l15) * 136 + l4 * 8];
        #pragma unroll
        for (int ks = 0; ks < 4; ks++) af[ks] = *(const s16x8*)(ab + ks * 32);
    }
    // GEMM: x @ W_ji -> silu -> xji (f32 scratch in d_out)
    #pragma unroll
    for (int cb = 0; cb < 8; cb++) {
        f32x4 acc = {0.f, 0.f, 0.f, 0.f};
        #pragma unroll
        for (int ks = 0; ks < 4; ks++) {
            s16x8 bf = *(const s16x8*)(wp + WJI + (((ks << 3) + cb) * 64 + l) * 8);
            acc = MFMA(af[ks], bf, acc);
        }
        int col = (cb << 4) + l15;
        float bv = bji[col];
        #pragma unroll
        for (int i = 0; i < 4; i++) {
            int r = w * 16 + l4 * 4 + i;
            xji[(size_t)(row0 + r) * 128 + col] = silu_f(acc[i] + bv);
        }
    }
    // GEMM: x @ W_kj -> silu -> * rbf_p -> LDS tile
    #pragma unroll
    for (int cb = 0; cb < 8; cb++) {
        f32x4 acc = {0.f, 0.f, 0.f, 0.f};
        #pragma unroll
        for (int ks = 0; ks < 4; ks++) {
            s16x8 bf = *(const s16x8*)(wp + WKJ + (((ks << 3) + cb) * 64 + l) * 8);
            acc = MFMA(af[ks], bf, acc);
        }
        int col = (cb << 4) + l15;
        float bv = bkj[col];
        #pragma unroll
        for (int i = 0; i < 4; i++) {
            int r = w * 16 + l4 * 4 + i;
            float v = silu_f(acc[i] + bv) * bf2f(rp[r * 128 + col]);
            kjt[r * 136 + col] = f2bf(v);
        }
    }
    __syncthreads();
    // GEMM: kj @ W_down -> silu -> xd
    s16x8 ag[4];
    {
        const unsigned short* ab = &kjt[(w * 16 + l15) * 136 + l4 * 8];
        #pragma unroll
        for (int ks = 0; ks < 4; ks++) ag[ks] = *(const s16x8*)(ab + ks * 32);
    }
    #pragma unroll
    for (int cb = 0; cb < 4; cb++) {
        f32x4 acc = {0.f, 0.f, 0.f, 0.f};
        #pragma unroll
        for (int ks = 0; ks < 4; ks++) {
            s16x8 bf = *(const s16x8*)(wp + WDOWN + (((ks << 2) + cb) * 64 + l) * 8);
            acc = MFMA(ag[ks], bf, acc);
        }
        int col = (cb << 4) + l15;
        #pragma unroll
        for (int i = 0; i < 4; i++) {
            int r = w * 16 + l4 * 4 + i;
            xd[(size_t)(row0 + r) * 64 + col] = silu_f(acc[i]);
        }
    }
}

// ============ K2: triplets: sbf_p (MFMA) -> gather -> scatter-add ============
__global__ __launch_bounds__(256) void k_trip(
        const float* __restrict__ sbf, const int* __restrict__ ikj, const int* __restrict__ iji,
        const unsigned short* __restrict__ wp, const float* __restrict__ xd,
        float* __restrict__ agg) {
    __shared__ unsigned short sb[64 * 72];
    const int tid = threadIdx.x;
    const int w = tid >> 6, l = tid & 63, l15 = l & 15, l4 = l >> 4;
    const int nchunk = (TN + 63) >> 6;
    for (int ch = blockIdx.x; ch < nchunk; ch += gridDim.x) {
        const int t0 = ch << 6;
        const int nt = min(64, TN - t0);
        for (int idx = tid; idx < 64 * 72; idx += 256) sb[idx] = 0;
        __syncthreads();
        const int tot = nt * 42;
        const float* src = sbf + (size_t)t0 * 42;
        for (int idx = tid; idx < tot; idx += 256) {
            int r = idx / 42, c = idx - r * 42;
            sb[r * 72 + c] = f2bf(src[idx]);
        }
        __syncthreads();
        s16x8 afr[2];
        {
            const unsigned short* ab = &sb[(w * 16 + l15) * 72 + l4 * 8];
            afr[0] = *(const s16x8*)ab;
            afr[1] = *(const s16x8*)(ab + 32);
        }
        #pragma unroll
        for (int cb = 0; cb < 4; cb++) {
            f32x4 acc = {0.f, 0.f, 0.f, 0.f};
            acc = MFMA(afr[0], *(const s16x8*)(wp + WSBFP + ((cb) * 64 + l) * 8), acc);
            acc = MFMA(afr[1], *(const s16x8*)(wp + WSBFP + ((4 + cb) * 64 + l) * 8), acc);
            int col = (cb << 4) + l15;
            #pragma unroll
            for (int i = 0; i < 4; i++) {
                int r = w * 16 + l4 * 4 + i;
                if (r < nt) {
                    int t = t0 + r;
                    int a = ikj[t], g = iji[t];
                    float m = acc[i] * xd[(size_t)a * 64 + col];
                    atomicAdd(&agg[(size_t)g * 64 + col], m);
                }
            }
        }
        __syncthreads();
    }
}

// residual MLP layer: h += silu(silu(h@W0+b0)@W1+b1), h fp32 in LDS
__device__ __forceinline__ void mm_layer(float* hh, unsigned short* aa, unsigned short* bb,
                                         const unsigned short* wp0, const float* b0,
                                         const unsigned short* wp1, const float* b1, int tid) {
    const int w = tid >> 6, l = tid & 63, l15 = l & 15, l4 = l >> 4;
    for (int idx = tid; idx < 8192; idx += 256) {
        int r = idx >> 7, c = idx & 127;
        aa[r * 136 + c] = f2bf(hh[r * 132 + c]);
    }
    __syncthreads();
    {
        const unsigned short* ab = &aa[(w * 16 + l15) * 136 + l4 * 8];
        s16x8 a0 = *(const s16x8*)ab, a1 = *(const s16x8*)(ab + 32);
        s16x8 a2 = *(const s16x8*)(ab + 64), a3 = *(const s16x8*)(ab + 96);
        #pragma unroll
        for (int cb = 0; cb < 8; cb++) {
            f32x4 acc = {0.f, 0.f, 0.f, 0.f};
            acc = MFMA(a0, *(const s16x8*)(wp0 + ((cb) * 64 + l) * 8), acc);
            acc = MFMA(a1, *(const s16x8*)(wp0 + ((8 + cb) * 64 + l) * 8), acc);
            acc = MFMA(a2, *(const s16x8*)(wp0 + ((16 + cb) * 64 + l) * 8), acc);
            acc = MFMA(a3, *(const s16x8*)(wp0 + ((24 + cb) * 64 + l) * 8), acc);
            int col = (cb << 4) + l15;
            float bv = b0[col];
            #pragma unroll
            for (int i = 0; i < 4; i++) {
                int r = w * 16 + l4 * 4 + i;
                bb[r * 136 + col] = f2bf(silu_f(acc[i] + bv));
            }
        }
    }
    __syncthreads();
    {
        const unsigned short* ab = &bb[(w * 16 + l15) * 136 + l4 * 8];
        s16x8 a0 = *(const s16x8*)ab, a1 = *(const s16x8*)(ab + 32);
        s16x8 a2 = *(const s16x8*)(ab + 64), a3 = *(const s16x8*)(ab + 96);
        #pragma unroll
        for (int cb = 0; cb < 8; cb++) {
            f32x4 acc = {0.f, 0.f, 0.f, 0.f};
            acc = MFMA(a0, *(const s16x8*)(wp1 + ((cb) * 64 + l) * 8), acc);
            acc = MFMA(a1, *(const s16x8*)(wp1 + ((8 + cb) * 64 + l) * 8), acc);
            acc = MFMA(a2, *(const s16x8*)(wp1 + ((16 + cb) * 64 + l) * 8), acc);
            acc = MFMA(a3, *(const s16x8*)(wp1 + ((24 + cb) * 64 + l) * 8), acc);
            int col = (cb << 4) + l15;
            float bv = b1[col];
            #pragma unroll
            for (int i = 0; i < 4; i++) {
                int r = w * 16 + l4 * 4 + i;
                hh[r * 132 + col] += silu_f(acc[i] + bv);
            }
        }
    }
    __syncthreads();
}

// ============ K3: edge stage 2 mega-fusion ============
__global__ __launch_bounds__(256) void k_edge2(
        const float* __restrict__ agg, const float* __restrict__ x,
        const unsigned short* __restrict__ wp, const float* __restrict__ bbef,
        const float* __restrict__ blin, const float* __restrict__ baft,
        float* __restrict__ out) {
    __shared__ float hh[64 * 132];
    __shared__ unsigned short aa[64 * 136];
    __shared__ unsigned short bb[64 * 136];
    const int tid = threadIdx.x;
    const int row0 = blockIdx.x * 64;
    const int w = tid >> 6, l = tid & 63, l15 = l & 15, l4 = l >> 4;
    // stage agg tile as bf16 (stride 72)
    {
        const float4* src = (const float4*)(agg + (size_t)row0 * 64);
        #pragma unroll
        for (int k = 0; k < 4; k++) {
            int idx = tid + k * 256;
            float4 v = src[idx];
            int flat = idx << 2, r = flat >> 6, c = flat & 63;
            ushort4 u; u.x = f2bf(v.x); u.y = f2bf(v.y); u.z = f2bf(v.z); u.w = f2bf(v.w);
            *(ushort4*)&aa[r * 72 + c] = u;
        }
    }
    // load x_ji tile into hh (x_ji lives in d_out as f32 scratch)
    {
        const float4* src = (const float4*)(out + (size_t)row0 * 128);
        #pragma unroll
        for (int k = 0; k < 8; k++) {
            int idx = tid + k * 256;
            float4 v = src[idx];
            int flat = idx << 2, r = flat >> 7, c = flat & 127;
            *(float4*)&hh[r * 132 + c] = v;
        }
    }
    __syncthreads();
    // h = x_ji + silu(agg @ W_up)
    {
        const unsigned short* ab = &aa[(w * 16 + l15) * 72 + l4 * 8];
        s16x8 a0 = *(const s16x8*)ab, a1 = *(const s16x8*)(ab + 32);
        #pragma unroll
        for (int cb = 0; cb < 8; cb++) {
            f32x4 acc = {0.f, 0.f, 0.f, 0.f};
            acc = MFMA(a0, *(const s16x8*)(wp + WUP + ((cb) * 64 + l) * 8), acc);
            acc = MFMA(a1, *(const s16x8*)(wp + WUP + ((8 + cb) * 64 + l) * 8), acc);
            int col = (cb << 4) + l15;
            #pragma unroll
            for (int i = 0; i < 4; i++) {
                int r = w * 16 + l4 * 4 + i;
                hh[r * 132 + col] += silu_f(acc[i]);
            }
        }
    }
    __syncthreads();
    // before-skip residual layer
    mm_layer(hh, aa, bb, wp + WB0, bbef, wp + WB1, bbef + 128, tid);
    // h = silu(h @ W_lin + b_lin) + x
    for (int idx = tid; idx < 8192; idx += 256) {
        int r = idx >> 7, c = idx & 127;
        aa[r * 136 + c] = f2bf(hh[r * 132 + c]);
    }
    __syncthreads();
    {
        const unsigned short* ab = &aa[(w * 16 + l15) * 136 + l4 * 8];
        s16x8 a0 = *(const s16x8*)ab, a1 = *(const s16x8*)(ab + 32);
        s16x8 a2 = *(const s16x8*)(ab + 64), a3 = *(const s16x8*)(ab + 96);
        #pragma unroll
        for (int cb = 0; cb < 8; cb++) {
            f32x4 acc = {0.f, 0.f, 0.f, 0.f};
            acc = MFMA(a0, *(const s16x8*)(wp + WLIN + ((cb) * 64 + l) * 8), acc);
            acc = MFMA(a1, *(const s16x8*)(wp + WLIN + ((8 + cb) * 64 + l) * 8), acc);
            acc = MFMA(a2, *(const s16x8*)(wp + WLIN + ((16 + cb) * 64 + l) * 8), acc);
            acc = MFMA(a3, *(const s16x8*)(wp + WLIN + ((24 + cb) * 64 + l) * 8), acc);
            int col = (cb << 4) + l15;
            float bv = blin[col];
            #pragma unroll
            for (int i = 0; i < 4; i++) {
                int r = w * 16 + l4 * 4 + i;
                float xv = x[(size_t)(row0 + r) * 128 + col];
                hh[r * 132 + col] = silu_f(acc[i] + bv) + xv;
            }
        }
    }
    __syncthreads();
    // after-skip residual layers
    mm_layer(hh, aa, bb, wp + WA00, baft, wp + WA01, baft + 128, tid);
    mm_layer(hh, aa, bb, wp + WA10, baft + 256, wp + WA11, baft + 384, tid);
    // store
    #pragma unroll
    for (int k = 0; k < 8; k++) {
        int idx = tid + k * 256;
        int flat = idx << 2, r = flat >> 7, c = flat & 127;
        *(float4*)&out[(size_t)row0 * 128 + flat] = *(const float4*)&hh[r * 132 + c];
    }
}

extern "C" void kernel_launch(void* const* d_in, const int* in_sizes, int n_in,
                              void* d_out, int out_size, void* d_ws, size_t ws_size,
                              hipStream_t stream) {
    const float* x     = (const float*)d_in[0];
    const float* rbf   = (const float*)d_in[1];
    const float* sbf   = (const float*)d_in[2];
    const int*   ikj   = (const int*)d_in[3];
    const int*   iji   = (const int*)d_in[4];
    const float* Wr1   = (const float*)d_in[5];
    const float* Wr2   = (const float*)d_in[6];
    const float* Ws1   = (const float*)d_in[7];
    const float* Ws2   = (const float*)d_in[8];
    const float* Wkj   = (const float*)d_in[9];
    const float* bkj   = (const float*)d_in[10];
    const float* Wji   = (const float*)d_in[11];
    const float* bji   = (const float*)d_in[12];
    const float* Wdown = (const float*)d_in[13];
    const float* Wup   = (const float*)d_in[14];
    const float* Wbef  = (const float*)d_in[15];
    const float* bbef  = (const float*)d_in[16];
    const float* Wlin  = (const float*)d_in[17];
    const float* blin  = (const float*)d_in[18];
    const float* Waft  = (const float*)d_in[19];
    const float* baft  = (const float*)d_in[20];

    char* ws = (char*)d_ws;
    float* agg           = (float*)ws;
    float* xd            = (float*)(ws + XD_OFF_B);
    unsigned short* wp   = (unsigned short*)(ws + WP_OFF_B);
    float* wrbfc         = (float*)(ws + WRBFC_OFF_B);
    float* wsbfc         = (float*)(ws + WSBFC_OFF_B);
    float* out           = (float*)d_out;

    hipMemsetAsync(agg, 0, AGG_BYTES, stream);
    k_prep1<<<14, 256, 0, stream>>>(Wr1, Wr2, Ws1, Ws2, wrbfc, wsbfc);
    k_prep2<<<656, 256, 0, stream>>>(Wji, Wkj, Wdown, Wup, Wbef, Wlin, Waft, wsbfc, wp);
    k_edge1<<<EN / 64, 256, 0, stream>>>(x, rbf, bkj, bji, wp, wrbfc, out, xd);
    k_trip<<<4096, 256, 0, stream>>>(sbf, ikj, iji, wp, xd, agg);
    k_edge2<<<EN / 64, 256, 0, stream>>>(agg, x, wp, bbef, blin, baft, out);
}